// Round 1
// 271.728 us; speedup vs baseline: 1.0553x; 1.0553x over previous
//
#include <hip/hip_runtime.h>

// ---------- helpers ----------
__device__ __forceinline__ unsigned short f2b(float f) {
    unsigned int u = __builtin_bit_cast(unsigned int, f);
    unsigned int r = (u + 0x7FFFu + ((u >> 16) & 1u)) >> 16;  // RNE
    return (unsigned short)r;
}
__device__ __forceinline__ float b2f(unsigned short s) {
    unsigned int u = ((unsigned int)s) << 16;
    return __builtin_bit_cast(float, u);
}

typedef __attribute__((ext_vector_type(8))) short short8;
typedef __attribute__((ext_vector_type(4))) float float4v;

#define GLD16(g, l) __builtin_amdgcn_global_load_lds(                          \
    (const __attribute__((address_space(1))) unsigned int*)(g),                \
    (__attribute__((address_space(3))) unsigned int*)(l), 16, 0, 0)

// L=16384, D_IN=512, D_H=1024, D_OUT=512
#define SEQLEN 16384
#define NCHUNK 512
#define TCHUNK 32
#define LDH 2560   // Hcat row stride (cols: [0,2048)=Bu/h, [2048,2560)=x_bf16)

// ---------- merged prep: xcast + prep_B + prep_CW ----------
__global__ void prep_all(const float* __restrict__ x,
                         const float* __restrict__ B_re, const float* __restrict__ B_im,
                         const float* __restrict__ gamma,
                         const float* __restrict__ C_re, const float* __restrict__ C_im,
                         const float* __restrict__ Dm,
                         unsigned short* __restrict__ Hcat,
                         unsigned short* __restrict__ Bcat,
                         unsigned short* __restrict__ CW) {
    int b = blockIdx.x;
    if (b < 8192) {
        int id = b * 256 + threadIdx.x;            // one per 4 elements of [16384 x 512]
        int t = id >> 7;
        int k4 = (id & 127) << 2;
        float4 v = *(const float4*)(x + (long)t * 512 + k4);
        ushort4 o;
        o.x = f2b(v.x); o.y = f2b(v.y); o.z = f2b(v.z); o.w = f2b(v.w);
        *(ushort4*)(Hcat + (long)t * LDH + 2048 + k4) = o;
    } else if (b < 9216) {
        int id = (b - 8192) * 256 + threadIdx.x;   // one per 4 elements of [2048 x 512]
        int n = id >> 7;
        int k4 = (id & 127) << 2;
        const float* src = (n < 1024) ? (B_re + (long)n * 512) : (B_im + (long)(n - 1024) * 512);
        float g = expf(gamma[n & 1023]);
        float4 v = *(const float4*)(src + k4);
        ushort4 o;
        o.x = f2b(v.x * g); o.y = f2b(v.y * g); o.z = f2b(v.z * g); o.w = f2b(v.w * g);
        *(ushort4*)(Bcat + (long)n * 512 + k4) = o;
    } else {
        int id = (b - 9216) * 256 + threadIdx.x;   // one per 4 elements of [512 x 2560]
        int o = id / 640;
        int j4 = (id - o * 640) << 2;
        float4 v; float sgn = 1.0f;
        if (j4 < 1024) {
            v = *(const float4*)(C_re + (long)o * 1024 + j4);
        } else if (j4 < 2048) {
            v = *(const float4*)(C_im + (long)o * 1024 + (j4 - 1024));
            sgn = -1.0f;
        } else {
            v = *(const float4*)(Dm + (long)o * 512 + (j4 - 2048));
        }
        ushort4 w;
        w.x = f2b(v.x * sgn); w.y = f2b(v.y * sgn); w.z = f2b(v.z * sgn); w.w = f2b(v.w * sgn);
        *(ushort4*)(CW + (long)o * 2560 + j4) = w;
    }
}

// ---------- 4-wave 128x128-tile GEMM (m97 structure) ----------
// 256 threads = 4 waves, tile 128(m) x 128(n), BK=32, double-buffered LDS.
// Per K-step per wave: 4x GLD16 staging, 8x ds_read_b128, 16x mfma_16x16x32_bf16.
// One __syncthreads per K-step: its implicit vmcnt(0)+lgkmcnt(0) drain is the
// staging handshake (m97 pattern, 874-912 TF verified at this geometry).
// LDS: 2 x (128x32 A + 128x32 B) bf16 = 32 KB -> 3 blocks/CU (VGPR-limited) = 3 waves/SIMD.
template <bool OUT_BF16>
__launch_bounds__(256, 3)
__global__ void gemm_t128(const unsigned short* __restrict__ A, int lda,
                          const unsigned short* __restrict__ B, int ldb,
                          void* __restrict__ Cout, int ldc, int Ktot,
                          int nbx_shift) {
    __shared__ unsigned short sm[2][8192] __attribute__((aligned(16)));
    const int lane = threadIdx.x & 63;
    const int wid = threadIdx.x >> 6;

    // bijective XCD swizzle: each XCD gets a contiguous by-range (grid % 8 == 0)
    const int bid = blockIdx.x;
    const int xcd = bid & 7;
    const int g = bid >> 3;
    const int bx = g & ((1 << nbx_shift) - 1);
    const int by = xcd * (gridDim.x >> (3 + nbx_shift)) + (g >> nbx_shift);
    const long m0 = (long)by * 128;
    const long n0 = (long)bx * 128;

    // staging: wave wid owns A rows [wid*32, wid*32+32) and B rows likewise.
    // One GLD16 = 64 lanes x 16B = 16 rows x 32 cols (1 KB), linear LDS layout.
    const int srow = lane >> 2;            // 0..15
    const int scol = (lane & 3) * 8;       // 0,8,16,24
    const unsigned short* Ag = A + (m0 + wid * 32 + srow) * (long)lda + scol;
    const unsigned short* Bg = B + (n0 + wid * 32 + srow) * (long)ldb + scol;

    // fragment addressing (16x16x32 bf16): row/col = lane&15, k = (lane>>4)*8
    const int fr = lane & 15;
    const int fk = (lane >> 4) * 8;
    const int wr = (wid >> 1) * 64;        // wave's 64x64 sub-tile
    const int wc = (wid & 1) * 64;

    float4v acc[4][4] = {};
    short8 fa[4], fb[4];

    auto stage = [&](unsigned short* buf, int k0) {
        GLD16(Ag + k0, buf + wid * 1024);
        GLD16(Ag + (long)16 * lda + k0, buf + wid * 1024 + 512);
        GLD16(Bg + k0, buf + 4096 + wid * 1024);
        GLD16(Bg + (long)16 * ldb + k0, buf + 4096 + wid * 1024 + 512);
    };
    auto loadfrags = [&](const unsigned short* buf) {
#pragma unroll
        for (int i = 0; i < 4; i++)
            fa[i] = *(const short8*)(buf + (wr + i * 16 + fr) * 32 + fk);
#pragma unroll
        for (int j = 0; j < 4; j++)
            fb[j] = *(const short8*)(buf + 4096 + (wc + j * 16 + fr) * 32 + fk);
    };

    const int nk = Ktot >> 5;
    unsigned short* pc = sm[0];
    unsigned short* pn = sm[1];
    stage(pc, 0);
#pragma unroll 2
    for (int t = 0; t < nk; ++t) {
        __syncthreads();                   // drains vmcnt(0): tile t landed (all waves)
        if (t + 1 < nk) stage(pn, (t + 1) * 32);
        loadfrags(pc);
#pragma unroll
        for (int mi = 0; mi < 4; mi++)
#pragma unroll
            for (int ni = 0; ni < 4; ni++)
                acc[mi][ni] = __builtin_amdgcn_mfma_f32_16x16x32_bf16(fa[mi], fb[ni], acc[mi][ni], 0, 0, 0);
        unsigned short* t2 = pc; pc = pn; pn = t2;
    }

    // epilogue: C/D layout col=lane&15, row=(lane>>4)*4+reg
    const int er = (lane >> 4) * 4;
    const int ec = lane & 15;
#pragma unroll
    for (int mi = 0; mi < 4; mi++) {
#pragma unroll
        for (int r = 0; r < 4; r++) {
            long grow = m0 + wr + mi * 16 + er + r;
#pragma unroll
            for (int ni = 0; ni < 4; ni++) {
                long gcol = n0 + wc + ni * 16 + ec;
                float v = acc[mi][ni][r];
                if (OUT_BF16)
                    ((unsigned short*)Cout)[grow * ldc + gcol] = f2b(v);
                else
                    ((float*)Cout)[grow * ldc + gcol] = v;
            }
        }
    }
}

// ---------- scan pass B: per-chunk local end states (zero-init) ----------
__global__ void scan_ends(const unsigned short* __restrict__ Hcat,
                          const float* __restrict__ lamb,
                          float* __restrict__ E) {
    const int chunk = blockIdx.x;
    const int ch = threadIdx.x << 2;   // 4 channels per thread
    float lre[4], lim[4];
#pragma unroll
    for (int i = 0; i < 4; i++) {
        float nu = expf(-expf(lamb[ch + i]));
        float th = expf(lamb[1024 + ch + i]);
        lre[i] = nu * cosf(th);
        lim[i] = nu * sinf(th);
    }
    float hr[4] = {0, 0, 0, 0}, hi[4] = {0, 0, 0, 0};
    const unsigned short* base = Hcat + (long)chunk * TCHUNK * LDH + ch;
#pragma unroll 4
    for (int t = 0; t < TCHUNK; t++) {
        ushort4 br = *(const ushort4*)(base + (long)t * LDH);
        ushort4 bi = *(const ushort4*)(base + (long)t * LDH + 1024);
        float brf[4] = {b2f(br.x), b2f(br.y), b2f(br.z), b2f(br.w)};
        float bif[4] = {b2f(bi.x), b2f(bi.y), b2f(bi.z), b2f(bi.w)};
#pragma unroll
        for (int i = 0; i < 4; i++) {
            float nr = fmaf(lre[i], hr[i], fmaf(-lim[i], hi[i], brf[i]));
            float ni = fmaf(lre[i], hi[i], fmaf(lim[i], hr[i], bif[i]));
            hr[i] = nr; hi[i] = ni;
        }
    }
    float* Ec = E + (long)chunk * 2048 + ch;
#pragma unroll
    for (int i = 0; i < 4; i++) {
        Ec[i] = hr[i];
        Ec[1024 + i] = hi[i];
    }
}

// ---------- scan pass C: sequential carry combine over chunks ----------
__global__ void carry(const float* __restrict__ lamb, const float* __restrict__ E,
                      float* __restrict__ Kc) {
    const int ch = blockIdx.x * 256 + threadIdx.x;  // 0..1023
    double nu = exp(-exp((double)lamb[ch]));
    double th = exp((double)lamb[1024 + ch]);
    double lr = nu * cos(th), li = nu * sin(th);
#pragma unroll
    for (int i = 0; i < 5; i++) {          // lambda^32
        double rr = lr * lr - li * li;
        double ii = 2.0 * lr * li;
        lr = rr; li = ii;
    }
    float tre = (float)lr, tim = (float)li;
    float hr = 0.0f, hi = 0.0f;
#pragma unroll 8
    for (int c = 0; c < NCHUNK; c++) {
        Kc[(long)c * 2048 + ch] = hr;
        Kc[(long)c * 2048 + 1024 + ch] = hi;
        float er = E[(long)c * 2048 + ch];
        float ei = E[(long)c * 2048 + 1024 + ch];
        float nr = fmaf(tre, hr, fmaf(-tim, hi, er));
        float ni = fmaf(tre, hi, fmaf(tim, hr, ei));
        hr = nr; hi = ni;
    }
}

// ---------- scan pass D: re-scan each chunk seeded with carry, IN PLACE ----------
__global__ void scan_apply(unsigned short* __restrict__ Hcat,
                           const float* __restrict__ lamb,
                           const float* __restrict__ Kc) {
    const int chunk = blockIdx.x;
    const int ch = threadIdx.x << 2;
    float lre[4], lim[4];
#pragma unroll
    for (int i = 0; i < 4; i++) {
        float nu = expf(-expf(lamb[ch + i]));
        float th = expf(lamb[1024 + ch + i]);
        lre[i] = nu * cosf(th);
        lim[i] = nu * sinf(th);
    }
    float hr[4], hi[4];
#pragma unroll
    for (int i = 0; i < 4; i++) {
        hr[i] = Kc[(long)chunk * 2048 + ch + i];
        hi[i] = Kc[(long)chunk * 2048 + 1024 + ch + i];
    }
    unsigned short* base = Hcat + (long)chunk * TCHUNK * LDH + ch;
#pragma unroll 4
    for (int t = 0; t < TCHUNK; t++) {
        ushort4 br = *(const ushort4*)(base + (long)t * LDH);
        ushort4 bi = *(const ushort4*)(base + (long)t * LDH + 1024);
        float brf[4] = {b2f(br.x), b2f(br.y), b2f(br.z), b2f(br.w)};
        float bif[4] = {b2f(bi.x), b2f(bi.y), b2f(bi.z), b2f(bi.w)};
#pragma unroll
        for (int i = 0; i < 4; i++) {
            float nr = fmaf(lre[i], hr[i], fmaf(-lim[i], hi[i], brf[i]));
            float ni = fmaf(lre[i], hi[i], fmaf(lim[i], hr[i], bif[i]));
            hr[i] = nr; hi[i] = ni;
        }
        ushort4 orv, oiv;
        orv.x = f2b(hr[0]); orv.y = f2b(hr[1]); orv.z = f2b(hr[2]); orv.w = f2b(hr[3]);
        oiv.x = f2b(hi[0]); oiv.y = f2b(hi[1]); oiv.z = f2b(hi[2]); oiv.w = f2b(hi[3]);
        *(ushort4*)(base + (long)t * LDH) = orv;
        *(ushort4*)(base + (long)t * LDH + 1024) = oiv;
    }
}

// ---------- launch ----------
extern "C" void kernel_launch(void* const* d_in, const int* in_sizes, int n_in,
                              void* d_out, int out_size, void* d_ws, size_t ws_size,
                              hipStream_t stream) {
    const float* x     = (const float*)d_in[0];  // [16384, 512]
    const float* lamb  = (const float*)d_in[1];  // [2, 1024]
    const float* gamma = (const float*)d_in[2];  // [1024]
    const float* B_re  = (const float*)d_in[3];  // [1024, 512]
    const float* B_im  = (const float*)d_in[4];
    const float* C_re  = (const float*)d_in[5];  // [512, 1024]
    const float* C_im  = (const float*)d_in[6];
    const float* Dm    = (const float*)d_in[7];  // [512, 512]

    char* ws = (char*)d_ws;
    unsigned short* Hcat = (unsigned short*)ws;                      // 16384*2560*2 = 83886080
    float* E  = (float*)(ws + 83886080);                             // 512*2048*4 = 4194304
    float* Kc = E + (long)NCHUNK * 2048;                             // 4194304
    unsigned short* Bcat = (unsigned short*)((char*)Kc + 4194304);   // 2048*512*2 = 2097152
    unsigned short* CW   = Bcat + (long)2048 * 512;                  // 512*2560*2 = 2621440

    prep_all<<<10496, 256, 0, stream>>>(x, B_re, B_im, gamma, C_re, C_im, Dm, Hcat, Bcat, CW);
    // Bu = x_bf16 @ Bcat^T -> Hcat cols [0,2048). grid: 128(by) x 16(bx) = 2048 blocks x 4 waves.
    gemm_t128<true><<<2048, 256, 0, stream>>>(Hcat + 2048, LDH, Bcat, 512, Hcat, LDH, 512,
                                              /*nbx_shift=*/4);
    scan_ends<<<NCHUNK, 256, 0, stream>>>(Hcat, lamb, E);
    carry<<<4, 256, 0, stream>>>(lamb, E, Kc);
    scan_apply<<<NCHUNK, 256, 0, stream>>>(Hcat, lamb, Kc);
    // y = Hcat @ CW^T -> d_out f32. grid: 128(by) x 4(bx) = 512 blocks x 4 waves.
    gemm_t128<false><<<512, 256, 0, stream>>>(Hcat, LDH, CW, 2560, (float*)d_out, 512, 2560,
                                              /*nbx_shift=*/2);
}

// Round 2
// 263.735 us; speedup vs baseline: 1.0873x; 1.0303x over previous
//
#include <hip/hip_runtime.h>

// ---------- helpers ----------
__device__ __forceinline__ unsigned short f2b(float f) {
    unsigned int u = __builtin_bit_cast(unsigned int, f);
    unsigned int r = (u + 0x7FFFu + ((u >> 16) & 1u)) >> 16;  // RNE
    return (unsigned short)r;
}
__device__ __forceinline__ float b2f(unsigned short s) {
    unsigned int u = ((unsigned int)s) << 16;
    return __builtin_bit_cast(float, u);
}

typedef __attribute__((ext_vector_type(8))) short short8;
typedef __attribute__((ext_vector_type(4))) float float4v;

#define GLD16(g, l) __builtin_amdgcn_global_load_lds(                          \
    (const __attribute__((address_space(1))) unsigned int*)(g),                \
    (__attribute__((address_space(3))) unsigned int*)(l), 16, 0, 0)

// s_waitcnt imm: vmcnt[3:0], expcnt[6:4], lgkmcnt[11:8] (exp/lgkm left free)
#define WAIT_VMN(n) __builtin_amdgcn_s_waitcnt(0x0F70 | (n))
#define SB()        __builtin_amdgcn_sched_barrier(0)
#define BAR()       __builtin_amdgcn_s_barrier()

// L=16384, D_IN=512, D_H=1024, D_OUT=512
#define SEQLEN 16384
#define NCHUNK 512
#define TCHUNK 32
#define LDH 2560   // Hcat row stride (cols: [0,2048)=Bu/h, [2048,2560)=x_bf16)

// ---------- merged prep: xcast + prep_B + prep_CW ----------
__global__ void prep_all(const float* __restrict__ x,
                         const float* __restrict__ B_re, const float* __restrict__ B_im,
                         const float* __restrict__ gamma,
                         const float* __restrict__ C_re, const float* __restrict__ C_im,
                         const float* __restrict__ Dm,
                         unsigned short* __restrict__ Hcat,
                         unsigned short* __restrict__ Bcat,
                         unsigned short* __restrict__ CW) {
    int b = blockIdx.x;
    if (b < 8192) {
        int id = b * 256 + threadIdx.x;            // one per 4 elements of [16384 x 512]
        int t = id >> 7;
        int k4 = (id & 127) << 2;
        float4 v = *(const float4*)(x + (long)t * 512 + k4);
        ushort4 o;
        o.x = f2b(v.x); o.y = f2b(v.y); o.z = f2b(v.z); o.w = f2b(v.w);
        *(ushort4*)(Hcat + (long)t * LDH + 2048 + k4) = o;
    } else if (b < 9216) {
        int id = (b - 8192) * 256 + threadIdx.x;   // one per 4 elements of [2048 x 512]
        int n = id >> 7;
        int k4 = (id & 127) << 2;
        const float* src = (n < 1024) ? (B_re + (long)n * 512) : (B_im + (long)(n - 1024) * 512);
        float g = expf(gamma[n & 1023]);
        float4 v = *(const float4*)(src + k4);
        ushort4 o;
        o.x = f2b(v.x * g); o.y = f2b(v.y * g); o.z = f2b(v.z * g); o.w = f2b(v.w * g);
        *(ushort4*)(Bcat + (long)n * 512 + k4) = o;
    } else {
        int id = (b - 9216) * 256 + threadIdx.x;   // one per 4 elements of [512 x 2560]
        int o = id / 640;
        int j4 = (id - o * 640) << 2;
        float4 v; float sgn = 1.0f;
        if (j4 < 1024) {
            v = *(const float4*)(C_re + (long)o * 1024 + j4);
        } else if (j4 < 2048) {
            v = *(const float4*)(C_im + (long)o * 1024 + (j4 - 1024));
            sgn = -1.0f;
        } else {
            v = *(const float4*)(Dm + (long)o * 512 + (j4 - 2048));
        }
        ushort4 w;
        w.x = f2b(v.x * sgn); w.y = f2b(v.y * sgn); w.z = f2b(v.z * sgn); w.w = f2b(v.w * sgn);
        *(ushort4*)(CW + (long)o * 2560 + j4) = w;
    }
}

// ---------- 8-wave phase-split GEMM (m201 geometry, counted vmcnt) ----------
// 512 threads = 8 waves (2 wave-rows x 4 wave-cols). Tile BM x 256, BK=64.
//   MREP=8 -> BM=256, per-wave 128x64, LDS 2x64KB=128KB, vmcnt(8)
//   MREP=4 -> BM=128, per-wave  64x64, LDS 2x48KB= 96KB, vmcnt(6)
// Per K-tile, 4 phases: {ds_read subtile | stage | bar | setprio+MFMA | bar}.
// Staging is consumption-ordered into the CURRENT buffer's already-consumed
// regions (B at P3 after its last read drains in P2; A at P4 after P3), so 2
// buffers suffice while loads for tile t+2 overlap compute of tile t..t+1.
// One counted vmcnt per K-tile (never 0 in steady state): outstanding =
// tile(t+1) GPT + tile(t+2) GPT -> WAIT_VMN(GPT) guarantees tile t+1 landed.
// LDS T2 swizzle: slot ^= (row&7); applied on the GLOBAL source (linear LDS
// dest, rule #21) and on the ds_read address. Kills the 16-way conflict.
template <int MREP, bool OUT_BF16>
__launch_bounds__(512, 2)
__global__ void gemm_8p(const unsigned short* __restrict__ A, int lda,
                        const unsigned short* __restrict__ B, int ldb,
                        void* __restrict__ Cout, int ldc, int Ktot,
                        int nbx_shift) {
    constexpr int BM  = MREP * 32;      // 256 or 128
    constexpr int ASH = BM * 64;        // A shorts per buffer
    constexpr int NA  = BM / 64;        // A-chunk GLD16s per wave per tile (4 or 2)
    constexpr int GPT = NA + 4;         // GLD16s per wave per tile (8 or 6)
    __shared__ unsigned short sm[2][ASH + 16384] __attribute__((aligned(16)));

    const int tid  = threadIdx.x;
    const int lane = tid & 63;
    const int wid  = tid >> 6;
    const int wr   = wid >> 2;          // wave row 0..1
    const int wc   = wid & 3;           // wave col 0..3

    // bijective XCD swizzle: each XCD owns a contiguous by-range (all bx)
    const int bid = blockIdx.x;
    const int xcd = bid & 7;
    const int g   = bid >> 3;
    const int bx  = g & ((1 << nbx_shift) - 1);
    const int by  = xcd * (gridDim.x >> (3 + nbx_shift)) + (g >> nbx_shift);
    const long m0 = (long)by * BM;
    const long n0 = (long)bx * 256;

    // staging: chunk = 8 rows x 64 cols (1KB). lane -> row (lane>>3),
    // global col-slot pre-swizzled: (lane&7) ^ (lane>>3). LDS dest linear.
    const int sr = lane >> 3;
    const int sc = ((lane & 7) ^ sr) << 3;            // shorts
    const unsigned short* Agl = A + (m0 + sr) * (long)lda + sc;
    const unsigned short* Bgl = B + (n0 + sr) * (long)ldb + sc;

    // fragment reads: row = base + fr; k-slot swizzled with (fr&7)
    const int fr = lane & 15;
    const int x7 = fr & 7;
    const int k0off = (((lane >> 4)    ) ^ x7) << 3;  // shorts, kh=0
    const int k1off = (((lane >> 4) + 4) ^ x7) << 3;  // shorts, kh=1

    float4v acc[MREP][4] = {};
    short8 fa[MREP / 2][2];
    short8 fb[4][2];

    auto stageB = [&](unsigned short* buf, long kt) {
        unsigned short* ldsB = buf + ASH + wid * 512;
        const unsigned short* gB = Bgl + kt;
#pragma unroll
        for (int i = 0; i < 4; i++)
            GLD16(gB + (long)(8 * (wid + 8 * i)) * ldb, ldsB + i * 4096);
    };
    auto stageA = [&](unsigned short* buf, long kt) {
        unsigned short* ldsA = buf + wid * 512;
        const unsigned short* gA = Agl + kt;
#pragma unroll
        for (int i = 0; i < NA; i++)
            GLD16(gA + (long)(8 * (wid + 8 * i)) * lda, ldsA + i * 4096);
    };
    auto ldA = [&](const unsigned short* buf, int mbase) {
#pragma unroll
        for (int i = 0; i < MREP / 2; i++) {
            const unsigned short* p = buf + (wr * (BM / 2) + (mbase + i) * 16 + fr) * 64;
            fa[i][0] = *(const short8*)(p + k0off);
            fa[i][1] = *(const short8*)(p + k1off);
        }
    };
    auto ldB = [&](const unsigned short* buf, int nbase) {
#pragma unroll
        for (int j = 0; j < 2; j++) {
            const unsigned short* p = buf + ASH + (wc * 64 + (nbase + j) * 16 + fr) * 64;
            fb[nbase + j][0] = *(const short8*)(p + k0off);
            fb[nbase + j][1] = *(const short8*)(p + k1off);
        }
    };
    auto mfmaQ = [&](int mbase, int nbase) {
        __builtin_amdgcn_s_setprio(1);
#pragma unroll
        for (int i = 0; i < MREP / 2; i++)
#pragma unroll
            for (int j = 0; j < 2; j++) {
                acc[mbase + i][nbase + j] = __builtin_amdgcn_mfma_f32_16x16x32_bf16(
                    fa[i][0], fb[nbase + j][0], acc[mbase + i][nbase + j], 0, 0, 0);
                acc[mbase + i][nbase + j] = __builtin_amdgcn_mfma_f32_16x16x32_bf16(
                    fa[i][1], fb[nbase + j][1], acc[mbase + i][nbase + j], 0, 0, 0);
            }
        __builtin_amdgcn_s_setprio(0);
    };

    const int nk = Ktot >> 6;  // K-tiles of 64 (8 for gemm1, 40 for gemm2)

    // prologue: stage tiles 0 and 1; wait tile 0 (counted), barrier
    stageB(sm[0], 0);  stageA(sm[0], 0);
    stageB(sm[1], 64); stageA(sm[1], 64);
    WAIT_VMN(GPT);
    SB(); BAR(); SB();

    for (int t = 0; t < nk; ++t) {
        unsigned short* cur = sm[t & 1];
        const bool st = (t + 2 < nk);
        const long kt2 = (long)(t + 2) * 64;
        // P1: ds A(m lower half) + B(n0-1); mfma Qmlo x n0-1
        ldA(cur, 0); ldB(cur, 0);
        SB(); BAR(); SB();
        mfmaQ(0, 0);
        SB(); BAR(); SB();
        // P2: ds B(n2-3); mfma Qmlo x n2-3   (B fully consumed after this)
        ldB(cur, 2);
        SB(); BAR(); SB();
        mfmaQ(0, 2);
        SB(); BAR(); SB();
        // P3: stage B(t+2) into cur's B region (safe: consumed in P2);
        //     ds A(m upper half); mfma Qmhi x n0-1  (A fully consumed after this)
        if (st) stageB(cur, kt2);
        ldA(cur, MREP / 2);
        SB(); BAR(); SB();
        mfmaQ(MREP / 2, 0);
        SB(); BAR(); SB();
        // P4: stage A(t+2) into cur's A region (safe: consumed in P3);
        //     mfma Qmhi x n2-3; counted vmcnt -> tile t+1 landed
        if (st) stageA(cur, kt2);
        SB();
        mfmaQ(MREP / 2, 2);
        if (st)              WAIT_VMN(GPT);
        else if (t + 1 < nk) WAIT_VMN(0);
        SB(); BAR(); SB();
    }

    // epilogue: C/D layout col=lane&15, row=(lane>>4)*4+reg
    const int er = (lane >> 4) * 4;
    const int ec = lane & 15;
#pragma unroll
    for (int mi = 0; mi < MREP; mi++) {
#pragma unroll
        for (int r = 0; r < 4; r++) {
            long grow = m0 + wr * (BM / 2) + mi * 16 + er + r;
#pragma unroll
            for (int nj = 0; nj < 4; nj++) {
                long gcol = n0 + wc * 64 + nj * 16 + ec;
                float v = acc[mi][nj][r];
                if (OUT_BF16)
                    ((unsigned short*)Cout)[grow * ldc + gcol] = f2b(v);
                else
                    ((float*)Cout)[grow * ldc + gcol] = v;
            }
        }
    }
}

// ---------- scan pass B: per-chunk local end states (zero-init) ----------
__global__ void scan_ends(const unsigned short* __restrict__ Hcat,
                          const float* __restrict__ lamb,
                          float* __restrict__ E) {
    const int chunk = blockIdx.x;
    const int ch = threadIdx.x << 2;   // 4 channels per thread
    float lre[4], lim[4];
#pragma unroll
    for (int i = 0; i < 4; i++) {
        float nu = expf(-expf(lamb[ch + i]));
        float th = expf(lamb[1024 + ch + i]);
        lre[i] = nu * cosf(th);
        lim[i] = nu * sinf(th);
    }
    float hr[4] = {0, 0, 0, 0}, hi[4] = {0, 0, 0, 0};
    const unsigned short* base = Hcat + (long)chunk * TCHUNK * LDH + ch;
#pragma unroll 4
    for (int t = 0; t < TCHUNK; t++) {
        ushort4 br = *(const ushort4*)(base + (long)t * LDH);
        ushort4 bi = *(const ushort4*)(base + (long)t * LDH + 1024);
        float brf[4] = {b2f(br.x), b2f(br.y), b2f(br.z), b2f(br.w)};
        float bif[4] = {b2f(bi.x), b2f(bi.y), b2f(bi.z), b2f(bi.w)};
#pragma unroll
        for (int i = 0; i < 4; i++) {
            float nr = fmaf(lre[i], hr[i], fmaf(-lim[i], hi[i], brf[i]));
            float ni = fmaf(lre[i], hi[i], fmaf(lim[i], hr[i], bif[i]));
            hr[i] = nr; hi[i] = ni;
        }
    }
    float* Ec = E + (long)chunk * 2048 + ch;
#pragma unroll
    for (int i = 0; i < 4; i++) {
        Ec[i] = hr[i];
        Ec[1024 + i] = hi[i];
    }
}

// ---------- scan pass C: sequential carry combine over chunks ----------
__global__ void carry(const float* __restrict__ lamb, const float* __restrict__ E,
                      float* __restrict__ Kc) {
    const int ch = blockIdx.x * 256 + threadIdx.x;  // 0..1023
    double nu = exp(-exp((double)lamb[ch]));
    double th = exp((double)lamb[1024 + ch]);
    double lr = nu * cos(th), li = nu * sin(th);
#pragma unroll
    for (int i = 0; i < 5; i++) {          // lambda^32
        double rr = lr * lr - li * li;
        double ii = 2.0 * lr * li;
        lr = rr; li = ii;
    }
    float tre = (float)lr, tim = (float)li;
    float hr = 0.0f, hi = 0.0f;
#pragma unroll 8
    for (int c = 0; c < NCHUNK; c++) {
        Kc[(long)c * 2048 + ch] = hr;
        Kc[(long)c * 2048 + 1024 + ch] = hi;
        float er = E[(long)c * 2048 + ch];
        float ei = E[(long)c * 2048 + 1024 + ch];
        float nr = fmaf(tre, hr, fmaf(-tim, hi, er));
        float ni = fmaf(tre, hi, fmaf(tim, hr, ei));
        hr = nr; hi = ni;
    }
}

// ---------- scan pass D: re-scan each chunk seeded with carry, IN PLACE ----------
__global__ void scan_apply(unsigned short* __restrict__ Hcat,
                           const float* __restrict__ lamb,
                           const float* __restrict__ Kc) {
    const int chunk = blockIdx.x;
    const int ch = threadIdx.x << 2;
    float lre[4], lim[4];
#pragma unroll
    for (int i = 0; i < 4; i++) {
        float nu = expf(-expf(lamb[ch + i]));
        float th = expf(lamb[1024 + ch + i]);
        lre[i] = nu * cosf(th);
        lim[i] = nu * sinf(th);
    }
    float hr[4], hi[4];
#pragma unroll
    for (int i = 0; i < 4; i++) {
        hr[i] = Kc[(long)chunk * 2048 + ch + i];
        hi[i] = Kc[(long)chunk * 2048 + 1024 + ch + i];
    }
    unsigned short* base = Hcat + (long)chunk * TCHUNK * LDH + ch;
#pragma unroll 4
    for (int t = 0; t < TCHUNK; t++) {
        ushort4 br = *(const ushort4*)(base + (long)t * LDH);
        ushort4 bi = *(const ushort4*)(base + (long)t * LDH + 1024);
        float brf[4] = {b2f(br.x), b2f(br.y), b2f(br.z), b2f(br.w)};
        float bif[4] = {b2f(bi.x), b2f(bi.y), b2f(bi.z), b2f(bi.w)};
#pragma unroll
        for (int i = 0; i < 4; i++) {
            float nr = fmaf(lre[i], hr[i], fmaf(-lim[i], hi[i], brf[i]));
            float ni = fmaf(lre[i], hi[i], fmaf(lim[i], hr[i], bif[i]));
            hr[i] = nr; hi[i] = ni;
        }
        ushort4 orv, oiv;
        orv.x = f2b(hr[0]); orv.y = f2b(hr[1]); orv.z = f2b(hr[2]); orv.w = f2b(hr[3]);
        oiv.x = f2b(hi[0]); oiv.y = f2b(hi[1]); oiv.z = f2b(hi[2]); oiv.w = f2b(hi[3]);
        *(ushort4*)(base + (long)t * LDH) = orv;
        *(ushort4*)(base + (long)t * LDH + 1024) = oiv;
    }
}

// ---------- launch ----------
extern "C" void kernel_launch(void* const* d_in, const int* in_sizes, int n_in,
                              void* d_out, int out_size, void* d_ws, size_t ws_size,
                              hipStream_t stream) {
    const float* x     = (const float*)d_in[0];  // [16384, 512]
    const float* lamb  = (const float*)d_in[1];  // [2, 1024]
    const float* gamma = (const float*)d_in[2];  // [1024]
    const float* B_re  = (const float*)d_in[3];  // [1024, 512]
    const float* B_im  = (const float*)d_in[4];
    const float* C_re  = (const float*)d_in[5];  // [512, 1024]
    const float* C_im  = (const float*)d_in[6];
    const float* Dm    = (const float*)d_in[7];  // [512, 512]

    char* ws = (char*)d_ws;
    unsigned short* Hcat = (unsigned short*)ws;                      // 16384*2560*2 = 83886080
    float* E  = (float*)(ws + 83886080);                             // 512*2048*4 = 4194304
    float* Kc = E + (long)NCHUNK * 2048;                             // 4194304
    unsigned short* Bcat = (unsigned short*)((char*)Kc + 4194304);   // 2048*512*2 = 2097152
    unsigned short* CW   = Bcat + (long)2048 * 512;                  // 512*2560*2 = 2621440

    prep_all<<<10496, 256, 0, stream>>>(x, B_re, B_im, gamma, C_re, C_im, Dm, Hcat, Bcat, CW);
    // Bu = x_bf16 @ Bcat^T -> Hcat cols [0,2048). BM=256: grid 64(by) x 8(bx) = 512 blocks.
    gemm_8p<8, true><<<512, 512, 0, stream>>>(Hcat + 2048, LDH, Bcat, 512, Hcat, LDH, 512,
                                              /*nbx_shift=*/3);
    scan_ends<<<NCHUNK, 256, 0, stream>>>(Hcat, lamb, E);
    carry<<<4, 256, 0, stream>>>(lamb, E, Kc);
    scan_apply<<<NCHUNK, 256, 0, stream>>>(Hcat, lamb, Kc);
    // y = Hcat @ CW^T -> d_out f32. BM=128: grid 128(by) x 2(bx) = 256 blocks.
    gemm_8p<4, false><<<256, 512, 0, stream>>>(Hcat, LDH, CW, 2560, (float*)d_out, 512, 2560,
                                               /*nbx_shift=*/1);
}

// Round 3
// 242.142 us; speedup vs baseline: 1.1842x; 1.0892x over previous
//
#include <hip/hip_runtime.h>

// ---------- helpers ----------
__device__ __forceinline__ unsigned short f2b(float f) {
    unsigned int u = __builtin_bit_cast(unsigned int, f);
    unsigned int r = (u + 0x7FFFu + ((u >> 16) & 1u)) >> 16;  // RNE
    return (unsigned short)r;
}
__device__ __forceinline__ float b2f(unsigned short s) {
    unsigned int u = ((unsigned int)s) << 16;
    return __builtin_bit_cast(float, u);
}

typedef __attribute__((ext_vector_type(8))) short short8;
typedef __attribute__((ext_vector_type(4))) float float4v;

#define GLD16(g, l) __builtin_amdgcn_global_load_lds(                          \
    (const __attribute__((address_space(1))) unsigned int*)(g),                \
    (__attribute__((address_space(3))) unsigned int*)(l), 16, 0, 0)

// s_waitcnt imm: vmcnt lo[3:0] hi[15:14], expcnt[6:4], lgkmcnt[11:8]
#define WAIT_VMN(n)  __builtin_amdgcn_s_waitcnt(0x0F70 | (n))   // vmcnt(n), lgkm/exp free
#define WAIT_LGKM0() __builtin_amdgcn_s_waitcnt(0xC07F)         // lgkmcnt(0), vm/exp free
#define SB()         __builtin_amdgcn_sched_barrier(0)
#define BAR()        __builtin_amdgcn_s_barrier()

// L=16384, D_IN=512, D_H=1024, D_OUT=512
#define SEQLEN 16384
#define NCHUNK 512
#define TCHUNK 32
#define LDH 2560   // Hcat row stride (cols: [0,2048)=Bu/h, [2048,2560)=x_bf16)

// ---------- merged prep: xcast + prep_B + prep_CW ----------
__global__ void prep_all(const float* __restrict__ x,
                         const float* __restrict__ B_re, const float* __restrict__ B_im,
                         const float* __restrict__ gamma,
                         const float* __restrict__ C_re, const float* __restrict__ C_im,
                         const float* __restrict__ Dm,
                         unsigned short* __restrict__ Hcat,
                         unsigned short* __restrict__ Bcat,
                         unsigned short* __restrict__ CW) {
    int b = blockIdx.x;
    if (b < 8192) {
        int id = b * 256 + threadIdx.x;            // one per 4 elements of [16384 x 512]
        int t = id >> 7;
        int k4 = (id & 127) << 2;
        float4 v = *(const float4*)(x + (long)t * 512 + k4);
        ushort4 o;
        o.x = f2b(v.x); o.y = f2b(v.y); o.z = f2b(v.z); o.w = f2b(v.w);
        *(ushort4*)(Hcat + (long)t * LDH + 2048 + k4) = o;
    } else if (b < 9216) {
        int id = (b - 8192) * 256 + threadIdx.x;   // one per 4 elements of [2048 x 512]
        int n = id >> 7;
        int k4 = (id & 127) << 2;
        const float* src = (n < 1024) ? (B_re + (long)n * 512) : (B_im + (long)(n - 1024) * 512);
        float g = expf(gamma[n & 1023]);
        float4 v = *(const float4*)(src + k4);
        ushort4 o;
        o.x = f2b(v.x * g); o.y = f2b(v.y * g); o.z = f2b(v.z * g); o.w = f2b(v.w * g);
        *(ushort4*)(Bcat + (long)n * 512 + k4) = o;
    } else {
        int id = (b - 9216) * 256 + threadIdx.x;   // one per 4 elements of [512 x 2560]
        int o = id / 640;
        int j4 = (id - o * 640) << 2;
        float4 v; float sgn = 1.0f;
        if (j4 < 1024) {
            v = *(const float4*)(C_re + (long)o * 1024 + j4);
        } else if (j4 < 2048) {
            v = *(const float4*)(C_im + (long)o * 1024 + (j4 - 1024));
            sgn = -1.0f;
        } else {
            v = *(const float4*)(Dm + (long)o * 512 + (j4 - 2048));
        }
        ushort4 w;
        w.x = f2b(v.x * sgn); w.y = f2b(v.y * sgn); w.z = f2b(v.z * sgn); w.w = f2b(v.w * sgn);
        *(ushort4*)(CW + (long)o * 2560 + j4) = w;
    }
}

// ---------- 8-wave phase-split GEMM (m201 geometry, counted vmcnt) ----------
// 512 threads = 8 waves (2 wave-rows x 4 wave-cols). Tile BM x 256, BK=64.
//   MREP=8 -> BM=256, 4 phases/K-tile, 16 MFMA/phase (m201 geometry)
//   MREP=4 -> BM=128, 2 phases/K-tile, 16 MFMA/phase (merged: halves barriers)
// Staging is consumption-ordered into the CURRENT buffer after its last read
// provably drained (lgkmcnt(0) pre-barrier where the read is in the same
// phase); one counted vmcnt per K-tile (never 0 in steady state).
// LDS T2 swizzle: slot ^= (row&7); pre-swizzled GLOBAL source + swizzled
// ds_read (rule #21). Bank conflicts measured 0.
template <int MREP, bool OUT_BF16>
__launch_bounds__(512, 2)
__global__ void gemm_8p(const unsigned short* __restrict__ A, int lda,
                        const unsigned short* __restrict__ B, int ldb,
                        void* __restrict__ Cout, int ldc, int Ktot,
                        int nbx_shift) {
    constexpr int BM  = MREP * 32;      // 256 or 128
    constexpr int ASH = BM * 64;        // A shorts per buffer
    constexpr int NA  = BM / 64;        // A-chunk GLD16s per wave per tile (4 or 2)
    constexpr int GPT = NA + 4;         // GLD16s per wave per tile (8 or 6)
    __shared__ unsigned short sm[2][ASH + 16384] __attribute__((aligned(16)));

    const int tid  = threadIdx.x;
    const int lane = tid & 63;
    const int wid  = tid >> 6;
    const int wr   = wid >> 2;          // wave row 0..1
    const int wc   = wid & 3;           // wave col 0..3

    // bijective XCD swizzle: each XCD owns a contiguous by-range (all bx)
    const int bid = blockIdx.x;
    const int xcd = bid & 7;
    const int g   = bid >> 3;
    const int bx  = g & ((1 << nbx_shift) - 1);
    const int by  = xcd * (gridDim.x >> (3 + nbx_shift)) + (g >> nbx_shift);
    const long m0 = (long)by * BM;
    const long n0 = (long)bx * 256;

    // staging: chunk = 8 rows x 64 cols (1KB). lane -> row (lane>>3),
    // global col-slot pre-swizzled: (lane&7) ^ (lane>>3). LDS dest linear.
    const int sr = lane >> 3;
    const int sc = ((lane & 7) ^ sr) << 3;            // shorts
    const unsigned short* Agl = A + (m0 + sr) * (long)lda + sc;
    const unsigned short* Bgl = B + (n0 + sr) * (long)ldb + sc;

    // fragment reads: row = base + fr; k-slot swizzled with (fr&7)
    const int fr = lane & 15;
    const int x7 = fr & 7;
    const int k0off = (((lane >> 4)    ) ^ x7) << 3;  // shorts, kh=0
    const int k1off = (((lane >> 4) + 4) ^ x7) << 3;  // shorts, kh=1

    float4v acc[MREP][4] = {};
    short8 fa[4][2];
    short8 fb[4][2];

    auto stageB = [&](unsigned short* buf, long kt) {
        unsigned short* ldsB = buf + ASH + wid * 512;
        const unsigned short* gB = Bgl + kt;
#pragma unroll
        for (int i = 0; i < 4; i++)
            GLD16(gB + (long)(8 * (wid + 8 * i)) * ldb, ldsB + i * 4096);
    };
    auto stageA = [&](unsigned short* buf, long kt) {
        unsigned short* ldsA = buf + wid * 512;
        const unsigned short* gA = Agl + kt;
#pragma unroll
        for (int i = 0; i < NA; i++)
            GLD16(gA + (long)(8 * (wid + 8 * i)) * lda, ldsA + i * 4096);
    };
    auto ldB = [&](const unsigned short* buf, int nbase) {
#pragma unroll
        for (int j = 0; j < 2; j++) {
            const unsigned short* p = buf + ASH + (wc * 64 + (nbase + j) * 16 + fr) * 64;
            fb[nbase + j][0] = *(const short8*)(p + k0off);
            fb[nbase + j][1] = *(const short8*)(p + k1off);
        }
    };

    const int nk = Ktot >> 6;  // K-tiles of 64 (8 for gemm1, 40 for gemm2)

    // prologue: stage tiles 0 and 1; wait tile 0 (counted), barrier
    stageB(sm[0], 0);  stageA(sm[0], 0);
    stageB(sm[1], 64); stageA(sm[1], 64);
    WAIT_VMN(GPT);
    SB(); BAR(); SB();

    if constexpr (MREP == 8) {
        auto ldA = [&](const unsigned short* buf, int mbase) {
#pragma unroll
            for (int i = 0; i < 4; i++) {
                const unsigned short* p = buf + (wr * 128 + (mbase + i) * 16 + fr) * 64;
                fa[i][0] = *(const short8*)(p + k0off);
                fa[i][1] = *(const short8*)(p + k1off);
            }
        };
        auto mfmaQ = [&](int mbase, int nbase) {
            __builtin_amdgcn_s_setprio(1);
#pragma unroll
            for (int i = 0; i < 4; i++)
#pragma unroll
                for (int j = 0; j < 2; j++) {
                    acc[mbase + i][nbase + j] = __builtin_amdgcn_mfma_f32_16x16x32_bf16(
                        fa[i][0], fb[nbase + j][0], acc[mbase + i][nbase + j], 0, 0, 0);
                    acc[mbase + i][nbase + j] = __builtin_amdgcn_mfma_f32_16x16x32_bf16(
                        fa[i][1], fb[nbase + j][1], acc[mbase + i][nbase + j], 0, 0, 0);
                }
            __builtin_amdgcn_s_setprio(0);
        };
        for (int t = 0; t < nk; ++t) {
            unsigned short* cur = sm[t & 1];
            const bool st = (t + 2 < nk);
            const long kt2 = (long)(t + 2) * 64;
            // P1: ds A(m lo) + B(n0-1); mfma Qmlo x n0-1
            ldA(cur, 0); ldB(cur, 0);
            SB(); BAR(); SB();
            mfmaQ(0, 0);
            SB(); BAR(); SB();
            // P2: ds B(n2-3); mfma Qmlo x n2-3  (B fully consumed after this)
            ldB(cur, 2);
            SB(); BAR(); SB();
            mfmaQ(0, 2);
            SB(); BAR(); SB();
            // P3: stage B(t+2) into cur (safe: B consumed in P2); ds A(m hi)
            if (st) stageB(cur, kt2);
            ldA(cur, 4);
            SB(); BAR(); SB();
            mfmaQ(4, 0);
            SB(); BAR(); SB();
            // P4: stage A(t+2) into cur (safe: A consumed in P3)
            if (st) stageA(cur, kt2);
            SB();
            mfmaQ(4, 2);
            if (st)              WAIT_VMN(GPT);
            else if (t + 1 < nk) WAIT_VMN(0);
            SB(); BAR(); SB();
        }
    } else {
        auto ldAall = [&](const unsigned short* buf) {
#pragma unroll
            for (int i = 0; i < 4; i++) {
                const unsigned short* p = buf + (wr * 64 + i * 16 + fr) * 64;
                fa[i][0] = *(const short8*)(p + k0off);
                fa[i][1] = *(const short8*)(p + k1off);
            }
        };
        auto mfmaN2 = [&](int nbase) {     // all 4 m x 2 n x 2 k = 16 MFMA
            __builtin_amdgcn_s_setprio(1);
#pragma unroll
            for (int i = 0; i < 4; i++)
#pragma unroll
                for (int j = 0; j < 2; j++) {
                    acc[i][nbase + j] = __builtin_amdgcn_mfma_f32_16x16x32_bf16(
                        fa[i][0], fb[nbase + j][0], acc[i][nbase + j], 0, 0, 0);
                    acc[i][nbase + j] = __builtin_amdgcn_mfma_f32_16x16x32_bf16(
                        fa[i][1], fb[nbase + j][1], acc[i][nbase + j], 0, 0, 0);
                }
            __builtin_amdgcn_s_setprio(0);
        };
        for (int t = 0; t < nk; ++t) {
            unsigned short* cur = sm[t & 1];
            const bool st = (t + 2 < nk);
            const long kt2 = (long)(t + 2) * 64;
            // P1: ds A(all 4 m) + B(n0-1); mfma all-m x n0-1 (16)
            ldAall(cur); ldB(cur, 0);
            SB(); BAR(); SB();
            mfmaN2(0);
            SB(); BAR(); SB();
            // P2: ds B(n2-3); drain lgkm (my reads done) then barrier (ALL
            // waves' reads done) -> in-place staging of tile t+2 is race-free;
            // mfma all-m x n2-3 (16); counted vmcnt -> tile t+1 landed.
            ldB(cur, 2);
            WAIT_LGKM0();
            SB(); BAR(); SB();
            if (st) { stageB(cur, kt2); stageA(cur, kt2); }
            SB();
            mfmaN2(2);
            if (st)              WAIT_VMN(GPT);
            else if (t + 1 < nk) WAIT_VMN(0);
            SB(); BAR(); SB();
        }
    }

    // epilogue: C/D layout col=lane&15, row=(lane>>4)*4+reg
    const int er = (lane >> 4) * 4;
    const int ec = lane & 15;
#pragma unroll
    for (int mi = 0; mi < MREP; mi++) {
#pragma unroll
        for (int r = 0; r < 4; r++) {
            long grow = m0 + wr * (BM / 2) + mi * 16 + er + r;
#pragma unroll
            for (int nj = 0; nj < 4; nj++) {
                long gcol = n0 + wc * 64 + nj * 16 + ec;
                float v = acc[mi][nj][r];
                if (OUT_BF16)
                    ((unsigned short*)Cout)[grow * ldc + gcol] = f2b(v);
                else
                    ((float*)Cout)[grow * ldc + gcol] = v;
            }
        }
    }
}

// ---------- scan pass B: per-chunk local end states (zero-init) ----------
__global__ void scan_ends(const unsigned short* __restrict__ Hcat,
                          const float* __restrict__ lamb,
                          float* __restrict__ E) {
    const int chunk = blockIdx.x;
    const int ch = threadIdx.x << 2;   // 4 channels per thread
    float lre[4], lim[4];
#pragma unroll
    for (int i = 0; i < 4; i++) {
        float nu = expf(-expf(lamb[ch + i]));
        float th = expf(lamb[1024 + ch + i]);
        lre[i] = nu * cosf(th);
        lim[i] = nu * sinf(th);
    }
    float hr[4] = {0, 0, 0, 0}, hi[4] = {0, 0, 0, 0};
    const unsigned short* base = Hcat + (long)chunk * TCHUNK * LDH + ch;
#pragma unroll 4
    for (int t = 0; t < TCHUNK; t++) {
        ushort4 br = *(const ushort4*)(base + (long)t * LDH);
        ushort4 bi = *(const ushort4*)(base + (long)t * LDH + 1024);
        float brf[4] = {b2f(br.x), b2f(br.y), b2f(br.z), b2f(br.w)};
        float bif[4] = {b2f(bi.x), b2f(bi.y), b2f(bi.z), b2f(bi.w)};
#pragma unroll
        for (int i = 0; i < 4; i++) {
            float nr = fmaf(lre[i], hr[i], fmaf(-lim[i], hi[i], brf[i]));
            float ni = fmaf(lre[i], hi[i], fmaf(lim[i], hr[i], bif[i]));
            hr[i] = nr; hi[i] = ni;
        }
    }
    float* Ec = E + (long)chunk * 2048 + ch;
#pragma unroll
    for (int i = 0; i < 4; i++) {
        Ec[i] = hr[i];
        Ec[1024 + i] = hi[i];
    }
}

// ---------- scan pass C: wave-parallel chunk-carry scan ----------
// One wave per channel (4 waves/block, 256 blocks). Lane l owns chunks
// [8l, 8l+8): sequential local combine (A_seg = T^8 const), then 6-step
// Kogge-Stone inclusive scan over lanes with operator
// (A2,b2)∘(A1,b1) = (A2*A1, A2*b1 + b2), then exclusive-seeded replay
// writing Kc. Replaces the 512-step serial latency chain (~N*latency)
// with ~16 dependent steps + 6 shuffles.
__global__ void carry(const float* __restrict__ lamb, const float* __restrict__ E,
                      float* __restrict__ Kc) {
    const int lane = threadIdx.x & 63;
    const int ch = blockIdx.x * 4 + (threadIdx.x >> 6);  // 0..1023
    double nu = exp(-exp((double)lamb[ch]));
    double th = exp((double)lamb[1024 + ch]);
    double lr = nu * cos(th), li = nu * sin(th);
#pragma unroll
    for (int i = 0; i < 5; i++) {          // T = lambda^32
        double rr = lr * lr - li * li;
        double ii = 2.0 * lr * li;
        lr = rr; li = ii;
    }
    const float tre = (float)lr, tim = (float)li;
    double ar = lr, ai = li;
#pragma unroll
    for (int i = 0; i < 3; i++) {          // T^8
        double rr = ar * ar - ai * ai;
        double ii = 2.0 * ar * ai;
        ar = rr; ai = ii;
    }
    float Ar = (float)ar, Ai = (float)ai;

    const int c0 = lane * 8;
    float er[8], ei[8];
#pragma unroll
    for (int j = 0; j < 8; j++) {
        er[j] = E[(long)(c0 + j) * 2048 + ch];
        ei[j] = E[(long)(c0 + j) * 2048 + 1024 + ch];
    }
    // local segment value from h=0
    float hr = 0.0f, hi = 0.0f;
#pragma unroll
    for (int j = 0; j < 8; j++) {
        float nr = fmaf(tre, hr, fmaf(-tim, hi, er[j]));
        float ni = fmaf(tre, hi, fmaf(tim, hr, ei[j]));
        hr = nr; hi = ni;
    }
    // inclusive Kogge-Stone across lanes
#pragma unroll
    for (int o = 1; o < 64; o <<= 1) {
        float pr = __shfl_up(hr, o);
        float pi = __shfl_up(hi, o);
        float qr = __shfl_up(Ar, o);
        float qi = __shfl_up(Ai, o);
        if (lane >= o) {
            float nr = fmaf(Ar, pr, fmaf(-Ai, pi, hr));
            float ni = fmaf(Ar, pi, fmaf(Ai, pr, hi));
            hr = nr; hi = ni;
            float nar = Ar * qr - Ai * qi;
            float nai = Ar * qi + Ai * qr;
            Ar = nar; Ai = nai;
        }
    }
    // exclusive seed = inclusive of lane-1 (lane 0 -> 0), then replay
    float sr = __shfl_up(hr, 1);
    float si = __shfl_up(hi, 1);
    if (lane == 0) { sr = 0.0f; si = 0.0f; }
#pragma unroll
    for (int j = 0; j < 8; j++) {
        Kc[(long)(c0 + j) * 2048 + ch] = sr;
        Kc[(long)(c0 + j) * 2048 + 1024 + ch] = si;
        float nr = fmaf(tre, sr, fmaf(-tim, si, er[j]));
        float ni = fmaf(tre, si, fmaf(tim, sr, ei[j]));
        sr = nr; si = ni;
    }
}

// ---------- scan pass D: re-scan each chunk seeded with carry, IN PLACE ----------
__global__ void scan_apply(unsigned short* __restrict__ Hcat,
                           const float* __restrict__ lamb,
                           const float* __restrict__ Kc) {
    const int chunk = blockIdx.x;
    const int ch = threadIdx.x << 2;
    float lre[4], lim[4];
#pragma unroll
    for (int i = 0; i < 4; i++) {
        float nu = expf(-expf(lamb[ch + i]));
        float th = expf(lamb[1024 + ch + i]);
        lre[i] = nu * cosf(th);
        lim[i] = nu * sinf(th);
    }
    float hr[4], hi[4];
#pragma unroll
    for (int i = 0; i < 4; i++) {
        hr[i] = Kc[(long)chunk * 2048 + ch + i];
        hi[i] = Kc[(long)chunk * 2048 + 1024 + ch + i];
    }
    unsigned short* base = Hcat + (long)chunk * TCHUNK * LDH + ch;
#pragma unroll 4
    for (int t = 0; t < TCHUNK; t++) {
        ushort4 br = *(const ushort4*)(base + (long)t * LDH);
        ushort4 bi = *(const ushort4*)(base + (long)t * LDH + 1024);
        float brf[4] = {b2f(br.x), b2f(br.y), b2f(br.z), b2f(br.w)};
        float bif[4] = {b2f(bi.x), b2f(bi.y), b2f(bi.z), b2f(bi.w)};
#pragma unroll
        for (int i = 0; i < 4; i++) {
            float nr = fmaf(lre[i], hr[i], fmaf(-lim[i], hi[i], brf[i]));
            float ni = fmaf(lre[i], hi[i], fmaf(lim[i], hr[i], bif[i]));
            hr[i] = nr; hi[i] = ni;
        }
        ushort4 orv, oiv;
        orv.x = f2b(hr[0]); orv.y = f2b(hr[1]); orv.z = f2b(hr[2]); orv.w = f2b(hr[3]);
        oiv.x = f2b(hi[0]); oiv.y = f2b(hi[1]); oiv.z = f2b(hi[2]); oiv.w = f2b(hi[3]);
        *(ushort4*)(base + (long)t * LDH) = orv;
        *(ushort4*)(base + (long)t * LDH + 1024) = oiv;
    }
}

// ---------- launch ----------
extern "C" void kernel_launch(void* const* d_in, const int* in_sizes, int n_in,
                              void* d_out, int out_size, void* d_ws, size_t ws_size,
                              hipStream_t stream) {
    const float* x     = (const float*)d_in[0];  // [16384, 512]
    const float* lamb  = (const float*)d_in[1];  // [2, 1024]
    const float* gamma = (const float*)d_in[2];  // [1024]
    const float* B_re  = (const float*)d_in[3];  // [1024, 512]
    const float* B_im  = (const float*)d_in[4];
    const float* C_re  = (const float*)d_in[5];  // [512, 1024]
    const float* C_im  = (const float*)d_in[6];
    const float* Dm    = (const float*)d_in[7];  // [512, 512]

    char* ws = (char*)d_ws;
    unsigned short* Hcat = (unsigned short*)ws;                      // 16384*2560*2 = 83886080
    float* E  = (float*)(ws + 83886080);                             // 512*2048*4 = 4194304
    float* Kc = E + (long)NCHUNK * 2048;                             // 4194304
    unsigned short* Bcat = (unsigned short*)((char*)Kc + 4194304);   // 2048*512*2 = 2097152
    unsigned short* CW   = Bcat + (long)2048 * 512;                  // 512*2560*2 = 2621440

    prep_all<<<10496, 256, 0, stream>>>(x, B_re, B_im, gamma, C_re, C_im, Dm, Hcat, Bcat, CW);
    // Bu = x_bf16 @ Bcat^T -> Hcat cols [0,2048). BM=256: grid 64(by) x 8(bx) = 512 blocks.
    gemm_8p<8, true><<<512, 512, 0, stream>>>(Hcat + 2048, LDH, Bcat, 512, Hcat, LDH, 512,
                                              /*nbx_shift=*/3);
    scan_ends<<<NCHUNK, 256, 0, stream>>>(Hcat, lamb, E);
    carry<<<256, 256, 0, stream>>>(lamb, E, Kc);
    scan_apply<<<NCHUNK, 256, 0, stream>>>(Hcat, lamb, Kc);
    // y = Hcat @ CW^T -> d_out f32. BM=128: grid 128(by) x 2(bx) = 256 blocks.
    gemm_8p<4, false><<<256, 512, 0, stream>>>(Hcat, LDH, CW, 2560, (float*)d_out, 512, 2560,
                                               /*nbx_shift=*/1);
}